// Round 8
// baseline (1905.505 us; speedup 1.0000x reference)
//
#include <hip/hip_runtime.h>
#include <cstdint>
#include <cstddef>

#define B_    4
#define L_    1024
#define ENCIN 64
#define DM    512
#define H_    8
#define HD    64
#define DFF   2048
#define NL    3
#define COUT  64
#define SCALE 0.125f
#define BH    32

typedef __attribute__((ext_vector_type(4))) short short4v;
typedef __attribute__((ext_vector_type(8))) short short8v;
typedef __attribute__((ext_vector_type(4))) float f32x4;
typedef unsigned short u16;
typedef unsigned char u8;

#define MFMA16(a,b,c) __builtin_amdgcn_mfma_f32_16x16x32_bf16(a,b,c,0,0,0)

#define GL2LDS(gsrc, ldst) \
  __builtin_amdgcn_global_load_lds( \
      (const __attribute__((address_space(1))) void*)(uintptr_t)(const void*)(gsrc), \
      (__attribute__((address_space(3))) void*)(uintptr_t)(const void*)(ldst), 16, 0, 0)

__device__ __forceinline__ u16 f2bf(float f){
  unsigned u = __float_as_uint(f);
  u += 0x7fffu + ((u >> 16) & 1u);              // RNE
  return (u16)(u >> 16);
}
__device__ __forceinline__ float bf2f(u16 h){
  return __uint_as_float(((unsigned)h) << 16);
}
__device__ __forceinline__ void split2(float v, u16* h, u16* l){
  u16 hh = f2bf(v);
  *h = hh;
  *l = f2bf(v - bf2f(hh));
}
__device__ __forceinline__ short8v cat8(short4v a, short4v b){
  return __builtin_shufflevector(a, b, 0,1,2,3,4,5,6,7);
}

// ---------------------------------------------------------------------------
// Split-bf16 MFMA GEMM, min-2-phase double-buffered. BM=128, BN=64/128,
// BK=32, 4 waves (2x2), wave tile 64 x BN/2. A=[M][K] hi/lo, B=W^T=[N][K].
// acc += Ah*Bh + Ah*Bl + Al*Bh.
// MODE: 0 fp32 out + bias; 1 emb (+PE, x fp32 + xh/xl); 2 gelu->split;
//       3 fused QKV epilogue; 5 split-K fp32 partial (z = blockIdx.z).
// ---------------------------------------------------------------------------
template<int BN, int MODE>
__global__ __launch_bounds__(256) void hgemm(
    const u16* __restrict__ Ah, const u16* __restrict__ Al,
    const u16* __restrict__ Bh, const u16* __restrict__ Bl,
    const float* __restrict__ bias1, const float* __restrict__ bias2,
    const float* __restrict__ bias3,
    float* __restrict__ o32, u16* __restrict__ oh, u16* __restrict__ ol,
    u16* __restrict__ oh2, u16* __restrict__ ol2, u16* __restrict__ ov,
    int Mtot, int N, int K, int klen)
{
  constexpr int NT = BN / 32;
  __shared__ u16 As[2][2][128*32];
  __shared__ u16 Bs[2][2][BN*32];
  const int t = threadIdx.x, lane = t & 63, wid = t >> 6;
  const int wr = wid >> 1, wc = wid & 1;
  const int fr = lane & 15, fq = lane >> 4;
  const int m0 = blockIdx.y * 128, n0 = blockIdx.x * BN;
  const int z = blockIdx.z;
  const int kbase = z * klen;
  const int srow = lane >> 2, sseg = lane & 3;

  const int nk = klen / 32;

  auto stage = [&](int buf, int kt) {
#pragma unroll
    for (int i = 0; i < 2; i++) {
      int c = wid + 4*i;
      GL2LDS(&Ah[(size_t)(m0 + c*16 + srow)*K + kt + sseg*8], &As[buf][0][c*512]);
      GL2LDS(&Al[(size_t)(m0 + c*16 + srow)*K + kt + sseg*8], &As[buf][1][c*512]);
    }
#pragma unroll
    for (int i = 0; i < BN/64; i++) {
      int c = wid + 4*i;
      GL2LDS(&Bh[(size_t)(n0 + c*16 + srow)*K + kt + sseg*8], &Bs[buf][0][c*512]);
      GL2LDS(&Bl[(size_t)(n0 + c*16 + srow)*K + kt + sseg*8], &Bs[buf][1][c*512]);
    }
  };

  f32x4 acc[4][NT] = {};
  stage(0, kbase);
  __syncthreads();

  for (int it = 0; it < nk; ++it) {
    int cur = it & 1;
    if (it + 1 < nk) stage(cur ^ 1, kbase + (it+1)*32);

    short8v a0[4], a1[4], b0[NT], b1[NT];
#pragma unroll
    for (int m = 0; m < 4; m++) {
      int off = (wr*64 + m*16 + fr)*32 + fq*4;
      a0[m] = cat8(*(const short4v*)&As[cur][0][off], *(const short4v*)&As[cur][0][off+16]);
      a1[m] = cat8(*(const short4v*)&As[cur][1][off], *(const short4v*)&As[cur][1][off+16]);
    }
#pragma unroll
    for (int n = 0; n < NT; n++) {
      int off = (wc*(BN/2) + n*16 + fr)*32 + fq*4;
      b0[n] = cat8(*(const short4v*)&Bs[cur][0][off], *(const short4v*)&Bs[cur][0][off+16]);
      b1[n] = cat8(*(const short4v*)&Bs[cur][1][off], *(const short4v*)&Bs[cur][1][off+16]);
    }
#pragma unroll
    for (int m = 0; m < 4; m++)
#pragma unroll
      for (int n = 0; n < NT; n++) {
        acc[m][n] = MFMA16(a0[m], b0[n], acc[m][n]);
        acc[m][n] = MFMA16(a0[m], b1[n], acc[m][n]);
        acc[m][n] = MFMA16(a1[m], b0[n], acc[m][n]);
      }
    __syncthreads();
  }

#pragma unroll
  for (int m = 0; m < 4; m++) {
#pragma unroll
    for (int n = 0; n < NT; n++) {
      int gc = n0 + wc*(BN/2) + n*16 + fr;
#pragma unroll
      for (int r = 0; r < 4; r++) {
        int row = m0 + wr*64 + m*16 + fq*4 + r;
        float v = acc[m][n][r];
        if (MODE == 5) {
          o32[((size_t)z*Mtot + row)*N + gc] = v;
        } else if (MODE == 0) {
          o32[(size_t)row*N + gc] = v + bias1[gc];
        } else if (MODE == 1) {
          v += bias1[gc];
          int li = row & (L_ - 1);
          float dv = expf((float)(gc & ~1) * -0.017988946039015984f);
          float ang = (float)li * dv;
          v += (gc & 1) ? cosf(ang) : sinf(ang);
          size_t ix = (size_t)row*N + gc;
          o32[ix] = v;
          split2(v, &oh[ix], &ol[ix]);
        } else if (MODE == 2) {
          v += bias1[gc];
          float gv = 0.5f * v * (1.0f + erff(v * 0.70710678118654752f));
          size_t ix = (size_t)row*N + gc;
          split2(gv, &oh[ix], &ol[ix]);
        } else if (MODE == 3) {
          int b = row >> 10, li = row & (L_ - 1);
          int sub = gc >> 9, h = (gc >> 6) & 7, d = gc & 63;
          if (sub == 0) {
            v += bias1[gc];
            size_t ix = (((size_t)(b*H_ + h))*L_ + li)*HD + d;
            split2(v, &oh[ix], &ol[ix]);
          } else if (sub == 1) {
            v += bias2[gc - 512];
            size_t ix = (((size_t)(b*H_ + h))*L_ + li)*HD + d;
            split2(v, &oh2[ix], &ol2[ix]);
          } else {
            v += bias3[gc - 1024];
            size_t ix = (((size_t)(b*H_ + h))*HD + d)*L_ + li;
            ov[ix] = f2bf(v);
          }
        }
      }
    }
  }
}

// ---------------------------------------------------------------------------
// count matrix: cnt[il][q][col] = multiplicity of col in sample_idx[il][q][:]
// ---------------------------------------------------------------------------
__global__ __launch_bounds__(256) void cnt_k(const int* __restrict__ sidx,
                                             u8* __restrict__ cnt)
{
  __shared__ unsigned c[L_];
  const int row = blockIdx.x, il = blockIdx.y, t = threadIdx.x;
#pragma unroll
  for (int i = 0; i < 4; i++) c[t + 256*i] = 0;
  __syncthreads();
  const int* ir = sidx + ((size_t)il*L_ + row)*L_;
#pragma unroll
  for (int i = 0; i < 4; i++) atomicAdd(&c[ir[t + 256*i]], 1u);
  __syncthreads();
  u8* out = cnt + ((size_t)il*L_ + row)*L_;
#pragma unroll
  for (int i = 0; i < 4; i++) out[t + 256*i] = (u8)c[t + 256*i];
}

// ---------------------------------------------------------------------------
// Shared S^T tile computation (bitwise identical in both attention passes).
// mfma(A=K, B=Q): lane holds S[q = lane&15][c = ct*64 + mi*16 + (lane>>4)*4+r]
// ---------------------------------------------------------------------------
__device__ __forceinline__ void st_tile(
    const u16* __restrict__ khb, const u16* __restrict__ klb,
    int ct, int fr, int fq, const short8v Qh[2], const short8v Ql[2],
    f32x4 sacc[4])
{
#pragma unroll
  for (int ks = 0; ks < 2; ks++) {
#pragma unroll
    for (int mi = 0; mi < 4; mi++) {
      const u16* ph = &khb[(size_t)(ct*64 + mi*16 + fr)*HD + ks*32 + fq*4];
      short8v ah = cat8(*(const short4v*)ph, *(const short4v*)(ph + 16));
      const u16* pl = &klb[(size_t)(ct*64 + mi*16 + fr)*HD + ks*32 + fq*4];
      short8v al = cat8(*(const short4v*)pl, *(const short4v*)(pl + 16));
      sacc[mi] = MFMA16(ah, Qh[ks], sacc[mi]);
      sacc[mi] = MFMA16(ah, Ql[ks], sacc[mi]);
      sacc[mi] = MFMA16(al, Qh[ks], sacc[mi]);
    }
  }
}

__device__ __forceinline__ void load_qfrags(
    const u16* __restrict__ qhb, const u16* __restrict__ qlb,
    int fr, int fq, short8v Qh[2], short8v Ql[2])
{
#pragma unroll
  for (int ks = 0; ks < 2; ks++) {
    const u16* p = &qhb[fr*HD + ks*32 + fq*4];
    Qh[ks] = cat8(*(const short4v*)p, *(const short4v*)(p + 16));
    const u16* p2 = &qlb[fr*HD + ks*32 + fq*4];
    Ql[ks] = cat8(*(const short4v*)p2, *(const short4v*)(p2 + 16));
  }
}

// XCD-chunked decode: each XCD owns 4 bh entirely (K/V stay L2-resident)
__device__ __forceinline__ void fdecode(int bid, int w, int& bh, int& q0)
{
  int xcd = bid & 7, ii = bid >> 3;
  bh = xcd*4 + (ii >> 4);
  q0 = (ii & 15)*64 + w*16;
}

// ---------------------------------------------------------------------------
// Attention pass 1: per-row softmax stats (rmax scaled, rsum) + sparsity
// measure Mv, computed from register-resident S^T tiles. No LDS, no barriers.
// ---------------------------------------------------------------------------
__global__ __launch_bounds__(256) void fqk_stat(
    const u16* __restrict__ qh, const u16* __restrict__ ql,
    const u16* __restrict__ kh, const u16* __restrict__ kl,
    const u8* __restrict__ cnt,
    float* __restrict__ rmx, float* __restrict__ rsm, float* __restrict__ Mv)
{
  const int t = threadIdx.x, lane = t & 63, w = t >> 6;
  const int fr = lane & 15, fq = lane >> 4;
  int bh, q0; fdecode(blockIdx.x, w, bh, q0);
  const u16* qhb = qh + ((size_t)bh*L_ + q0)*HD;
  const u16* qlb = ql + ((size_t)bh*L_ + q0)*HD;
  const u16* khb = kh + (size_t)bh*L_*HD;
  const u16* klb = kl + (size_t)bh*L_*HD;
  const u8* crow = cnt + (size_t)(q0 + fr)*L_;

  short8v Qh[2], Ql[2];
  load_qfrags(qhb, qlb, fr, fq, Qh, Ql);

  float run_m = -1e30f, run_s = 0.f, smp_m = -1e30f, wsum = 0.f;

#pragma unroll 4
  for (int ct = 0; ct < 16; ct++) {
    f32x4 sacc[4] = {};
    st_tile(khb, klb, ct, fr, fq, Qh, Ql, sacc);

    // per-lane online softmax over this lane's 16 columns
    float tmax = sacc[0][0];
#pragma unroll
    for (int mi = 0; mi < 4; mi++)
#pragma unroll
      for (int r = 0; r < 4; r++) tmax = fmaxf(tmax, sacc[mi][r]);
    float zm = tmax * SCALE;
    float tsum = 0.f;
#pragma unroll
    for (int mi = 0; mi < 4; mi++)
#pragma unroll
      for (int r = 0; r < 4; r++) tsum += expf(sacc[mi][r]*SCALE - zm);
    float nm = fmaxf(run_m, zm);
    run_s = run_s*expf(run_m - nm) + tsum*expf(zm - nm);
    run_m = nm;

    // sampled stats (count-weighted)
#pragma unroll
    for (int mi = 0; mi < 4; mi++) {
      unsigned cw = *(const unsigned*)&crow[ct*64 + mi*16 + fq*4];
#pragma unroll
      for (int r = 0; r < 4; r++) {
        float cf = (float)((cw >> (8*r)) & 255u);
        float s = sacc[mi][r];
        wsum += cf * s;
        if (cf > 0.f) smp_m = fmaxf(smp_m, s);
      }
    }
  }

  // combine the 4 lanes (fq groups) sharing each q
#pragma unroll
  for (int mask = 16; mask <= 32; mask <<= 1) {
    float om = __shfl_xor(run_m, mask);
    float os = __shfl_xor(run_s, mask);
    float nm = fmaxf(run_m, om);
    run_s = run_s*expf(run_m - nm) + os*expf(om - nm);
    run_m = nm;
    smp_m = fmaxf(smp_m, __shfl_xor(smp_m, mask));
    wsum += __shfl_xor(wsum, mask);
  }

  if (fq == 0) {
    size_t ix = (size_t)bh*L_ + q0 + fr;
    rmx[ix] = run_m;
    rsm[ix] = run_s;
    Mv[ix]  = smp_m - wsum * (1.0f / L_);
  }
}

// ---------------------------------------------------------------------------
// Full descending sort of M per (b,h) -> rank[orig] = sorted position
// ---------------------------------------------------------------------------
__global__ __launch_bounds__(1024) void sort_k(const float* __restrict__ Mv,
                                               int* __restrict__ rank)
{
  __shared__ unsigned long long keys[L_];
  const int bh = blockIdx.x, t = threadIdx.x;
  float m = Mv[(size_t)bh * L_ + t];
  unsigned u = __float_as_uint(m);
  u = (u & 0x80000000u) ? ~u : (u | 0x80000000u);
  keys[t] = ((unsigned long long)(~u) << 32) | (unsigned)t;
  __syncthreads();
  for (int k = 2; k <= L_; k <<= 1) {
    for (int j = k >> 1; j > 0; j >>= 1) {
      int ixj = t ^ j;
      if (ixj > t) {
        unsigned long long a = keys[t], b = keys[ixj];
        bool up = ((t & k) == 0);
        if ((a > b) == up) { keys[t] = b; keys[ixj] = a; }
      }
      __syncthreads();
    }
  }
  int orig = (int)(keys[t] & 0xFFFFFFFFu);
  rank[(size_t)bh * L_ + orig] = t;
}

// ---------------------------------------------------------------------------
// Attention pass 2: recompute S^T tiles (bitwise identical), P in registers
// (swapped C-frag == PV A-frag), PV MFMA, permuted split-bf16 output.
// ---------------------------------------------------------------------------
__global__ __launch_bounds__(256) void fpv(
    const u16* __restrict__ qh, const u16* __restrict__ ql,
    const u16* __restrict__ kh, const u16* __restrict__ kl,
    const u16* __restrict__ vt,
    const float* __restrict__ rmx, const float* __restrict__ rsm,
    const int* __restrict__ rank,
    u16* __restrict__ ath, u16* __restrict__ atl)
{
  const int t = threadIdx.x, lane = t & 63, w = t >> 6;
  const int fr = lane & 15, fq = lane >> 4;
  int bh, q0; fdecode(blockIdx.x, w, bh, q0);
  const int bb = bh >> 3, hh = bh & 7;
  const u16* qhb = qh + ((size_t)bh*L_ + q0)*HD;
  const u16* qlb = ql + ((size_t)bh*L_ + q0)*HD;
  const u16* khb = kh + (size_t)bh*L_*HD;
  const u16* klb = kl + (size_t)bh*L_*HD;
  const u16* vtb = vt + (size_t)bh*HD*L_;

  short8v Qh[2], Ql[2];
  load_qfrags(qhb, qlb, fr, fq, Qh, Ql);

  const float mq = rmx[(size_t)bh*L_ + q0 + fr];   // q = fr for P-frags

  f32x4 pacc[4] = {};

#pragma unroll 4
  for (int ct = 0; ct < 16; ct++) {
    f32x4 sacc[4] = {};
    st_tile(khb, klb, ct, fr, fq, Qh, Ql, sacc);

#pragma unroll
    for (int kt = 0; kt < 2; kt++) {
      short8v pa;
#pragma unroll
      for (int j = 0; j < 4; j++) {
        pa[j]   = (short)f2bf(expf(sacc[2*kt][j]  *SCALE - mq));
        pa[j+4] = (short)f2bf(expf(sacc[2*kt+1][j]*SCALE - mq));
      }
#pragma unroll
      for (int nd = 0; nd < 4; nd++) {
        const u16* pv = &vtb[(size_t)(nd*16 + fr)*L_ + ct*64 + kt*32 + fq*4];
        short8v bv = cat8(*(const short4v*)pv, *(const short4v*)(pv + 16));
        pacc[nd] = MFMA16(pa, bv, pacc[nd]);
      }
    }
  }

  // epilogue: D[row=q=fq*4+r][col=d=nd*16+fr]; write to permuted row rank[q]
  float rs[4]; int uu[4];
#pragma unroll
  for (int r = 0; r < 4; r++) {
    rs[r] = rsm[(size_t)bh*L_ + q0 + fq*4 + r];
    uu[r] = rank[(size_t)bh*L_ + q0 + fq*4 + r];
  }
#pragma unroll
  for (int nd = 0; nd < 4; nd++)
#pragma unroll
    for (int r = 0; r < 4; r++) {
      float o = pacc[nd][r] / rs[r];
      size_t ix = ((size_t)bb*L_ + uu[r])*DM + hh*HD + nd*16 + fr;
      split2(o, &ath[ix], &atl[ix]);
    }
}

// ---------------------------------------------------------------------------
// LayerNorm + optional split-K partial reduce + bias (fp32 + split bf16 out)
// ---------------------------------------------------------------------------
__global__ __launch_bounds__(64) void ln2_k(const float* __restrict__ xin,
    const float* __restrict__ part, int np, const float* __restrict__ bias,
    const float* __restrict__ g, const float* __restrict__ bb,
    float* __restrict__ out, u16* __restrict__ oh, u16* __restrict__ ol)
{
  const int row = blockIdx.x, t = threadIdx.x;
  const float4* xf = (const float4*)(xin + (size_t)row * DM);
  float4 v0 = xf[t], v1 = xf[t + 64];
  for (int p = 0; p < np; p++) {
    const float4* af = (const float4*)(part + ((size_t)p*(B_*L_) + row) * DM);
    float4 a0 = af[t], a1 = af[t + 64];
    v0.x += a0.x; v0.y += a0.y; v0.z += a0.z; v0.w += a0.w;
    v1.x += a1.x; v1.y += a1.y; v1.z += a1.z; v1.w += a1.w;
  }
  if (bias) {
    const float4* cf = (const float4*)bias;
    float4 c0 = cf[t], c1 = cf[t + 64];
    v0.x += c0.x; v0.y += c0.y; v0.z += c0.z; v0.w += c0.w;
    v1.x += c1.x; v1.y += c1.y; v1.z += c1.z; v1.w += c1.w;
  }
  float s  = v0.x + v0.y + v0.z + v0.w + v1.x + v1.y + v1.z + v1.w;
  float ss = v0.x*v0.x + v0.y*v0.y + v0.z*v0.z + v0.w*v0.w +
             v1.x*v1.x + v1.y*v1.y + v1.z*v1.z + v1.w*v1.w;
#pragma unroll
  for (int o = 32; o > 0; o >>= 1) { s += __shfl_xor(s, o); ss += __shfl_xor(ss, o); }
  float mean = s * (1.0f / DM);
  float var  = ss * (1.0f / DM) - mean * mean;
  float inv  = 1.0f / sqrtf(var + 1e-5f);
  const float4* gf = (const float4*)g;
  const float4* bf = (const float4*)bb;
  float4 g0 = gf[t], g1 = gf[t + 64], b0 = bf[t], b1 = bf[t + 64];
  float o0[4], o1[4];
  o0[0] = (v0.x-mean)*inv*g0.x + b0.x; o0[1] = (v0.y-mean)*inv*g0.y + b0.y;
  o0[2] = (v0.z-mean)*inv*g0.z + b0.z; o0[3] = (v0.w-mean)*inv*g0.w + b0.w;
  o1[0] = (v1.x-mean)*inv*g1.x + b1.x; o1[1] = (v1.y-mean)*inv*g1.y + b1.y;
  o1[2] = (v1.z-mean)*inv*g1.z + b1.z; o1[3] = (v1.w-mean)*inv*g1.w + b1.w;
  float4* of = (float4*)(out + (size_t)row * DM);
  of[t]      = make_float4(o0[0], o0[1], o0[2], o0[3]);
  of[t + 64] = make_float4(o1[0], o1[1], o1[2], o1[3]);
  size_t base = (size_t)row * DM;
#pragma unroll
  for (int j = 0; j < 4; j++) {
    split2(o0[j], &oh[base + t*4 + j],       &ol[base + t*4 + j]);
    split2(o1[j], &oh[base + 256 + t*4 + j], &ol[base + 256 + t*4 + j]);
  }
}

// ---------------------------------------------------------------------------
// split-K partial reduce + bias for the final projection (fp32 out)
// ---------------------------------------------------------------------------
__global__ __launch_bounds__(256) void rp_k(const float* __restrict__ part,
    const float* __restrict__ bias, float* __restrict__ out, int n)
{
  int i = blockIdx.x * 256 + threadIdx.x;
  if (i < n) {
    float v = bias[i & (COUT-1)];
#pragma unroll
    for (int z = 0; z < 4; z++) v += part[(size_t)z*n + i];
    out[i] = v;
  }
}

// ---------------------------------------------------------------------------
// Weight transpose + split: W [K][N] fp32 -> Th, Tl [N][K] bf16 (batched z)
// ---------------------------------------------------------------------------
__global__ __launch_bounds__(256) void wt_k(const float* __restrict__ W,
    u16* __restrict__ Th, u16* __restrict__ Tl, int K, int N,
    size_t wz, size_t tz)
{
  W  += (size_t)blockIdx.z * wz;
  Th += (size_t)blockIdx.z * tz;
  Tl += (size_t)blockIdx.z * tz;
  __shared__ float tile[32][33];
  const int k0 = blockIdx.y * 32, n0 = blockIdx.x * 32;
  const int c = threadIdx.x & 31, r4 = threadIdx.x >> 5;
#pragma unroll
  for (int i = 0; i < 4; i++) {
    int r = r4 * 4 + i;
    tile[r][c] = W[(size_t)(k0 + r) * N + n0 + c];
  }
  __syncthreads();
#pragma unroll
  for (int i = 0; i < 4; i++) {
    int r = r4 * 4 + i;
    float v = tile[c][r];
    split2(v, &Th[(size_t)(n0 + r) * K + k0 + c], &Tl[(size_t)(n0 + r) * K + k0 + c]);
  }
}

__global__ __launch_bounds__(256) void split_k(const float* __restrict__ in,
    u16* __restrict__ oh, u16* __restrict__ ol, int n4)
{
  int i = blockIdx.x * 256 + threadIdx.x;
  if (i < n4) {
    float4 v = ((const float4*)in)[i];
    split2(v.x, &oh[i*4+0], &ol[i*4+0]);
    split2(v.y, &oh[i*4+1], &ol[i*4+1]);
    split2(v.z, &oh[i*4+2], &ol[i*4+2]);
    split2(v.w, &oh[i*4+3], &ol[i*4+3]);
  }
}

// ---------------------------------------------------------------------------
extern "C" void kernel_launch(void* const* d_in, const int* in_sizes, int n_in,
                              void* d_out, int out_size, void* d_ws, size_t ws_size,
                              hipStream_t stream)
{
  const float* x_enc   = (const float*)d_in[0];
  const int*   sidx    = (const int*)d_in[1];
  const float* W_emb   = (const float*)d_in[2];
  const float* b_emb   = (const float*)d_in[3];
  const float* Wq      = (const float*)d_in[4];
  const float* bq      = (const float*)d_in[5];
  const float* Wk      = (const float*)d_in[6];
  const float* bk      = (const float*)d_in[7];
  const float* Wv      = (const float*)d_in[8];
  const float* bv      = (const float*)d_in[9];
  const float* Wo      = (const float*)d_in[10];
  const float* bo      = (const float*)d_in[11];
  const float* W1      = (const float*)d_in[12];
  const float* b1      = (const float*)d_in[13];
  const float* W2      = (const float*)d_in[14];
  const float* b2      = (const float*)d_in[15];
  const float* g1      = (const float*)d_in[16];
  const float* be1     = (const float*)d_in[17];
  const float* g2      = (const float*)d_in[18];
  const float* be2     = (const float*)d_in[19];
  const float* gN      = (const float*)d_in[20];
  const float* bN      = (const float*)d_in[21];
  const float* W_proj  = (const float*)d_in[22];
  const float* b_proj  = (const float*)d_in[23];

  const int M = B_ * L_;                          // 4096
  char* w = (char*)d_ws;
  float* x   = (float*)w;  w += (size_t)M * DM * 4;
  u16* xh    = (u16*)w;    w += (size_t)M * DM * 2;
  u16* xl    = (u16*)w;    w += (size_t)M * DM * 2;
  u16* qh_   = (u16*)w;    w += (size_t)BH * L_ * HD * 2;
  u16* ql_   = (u16*)w;    w += (size_t)BH * L_ * HD * 2;
  u16* kh_   = (u16*)w;    w += (size_t)BH * L_ * HD * 2;
  u16* kl_   = (u16*)w;    w += (size_t)BH * L_ * HD * 2;
  u16* vt_   = (u16*)w;    w += (size_t)BH * L_ * HD * 2;
  u16* ath   = (u16*)w;    w += (size_t)M * DM * 2;
  u16* atl   = (u16*)w;    w += (size_t)M * DM * 2;
  float* rmx_ = (float*)w; w += (size_t)BH * L_ * 4;
  float* rsm_ = (float*)w; w += (size_t)BH * L_ * 4;
  float* Mv_  = (float*)w; w += (size_t)BH * L_ * 4;
  int* rank_  = (int*)w;   w += (size_t)BH * L_ * 4;
  u8* cnt_    = (u8*)w;    w += (size_t)NL * L_ * L_;          // 3 MB
  u16* yh     = (u16*)w;   w += (size_t)M * DFF * 2;           // 16 MB
  u16* yl     = (u16*)w;   w += (size_t)M * DFF * 2;           // 16 MB
  float* partWo = (float*)w; w += (size_t)2 * M * DM * 4;      // 16 MB
  float* partW2 = (float*)w; w += (size_t)4 * M * DM * 4;      // 32 MB
  float* partPj = (float*)w; w += (size_t)4 * M * COUT * 4;    // 4 MB
  u16* xeh    = (u16*)w;   w += (size_t)M * ENCIN * 2;
  u16* xel    = (u16*)w;   w += (size_t)M * ENCIN * 2;
  // persistent transposed/split weights
  u16* WqkvTh = (u16*)w; w += (size_t)NL*1536*DM*2;
  u16* WqkvTl = (u16*)w; w += (size_t)NL*1536*DM*2;
  u16* WoTh   = (u16*)w; w += (size_t)NL*DM*DM*2;
  u16* WoTl   = (u16*)w; w += (size_t)NL*DM*DM*2;
  u16* W1Th   = (u16*)w; w += (size_t)NL*DFF*DM*2;
  u16* W1Tl   = (u16*)w; w += (size_t)NL*DFF*DM*2;
  u16* W2Th   = (u16*)w; w += (size_t)NL*DM*DFF*2;
  u16* W2Tl   = (u16*)w; w += (size_t)NL*DM*DFF*2;
  u16* WeTh   = (u16*)w; w += (size_t)DM*ENCIN*2;
  u16* WeTl   = (u16*)w; w += (size_t)DM*ENCIN*2;
  u16* WpTh   = (u16*)w; w += (size_t)COUT*DM*2;
  u16* WpTl   = (u16*)w; w += (size_t)COUT*DM*2;

  // --- one-time: input split, count matrices, weight transposes ---
  split_k<<<dim3((M*ENCIN/4 + 255)/256), 256, 0, stream>>>(x_enc, xeh, xel, M*ENCIN/4);
  cnt_k<<<dim3(L_, NL), 256, 0, stream>>>(sidx, cnt_);
  wt_k<<<dim3(DM/32, DM/32, NL), 256, 0, stream>>>(Wq, WqkvTh,           WqkvTl,           DM, DM, (size_t)DM*DM, (size_t)1536*DM);
  wt_k<<<dim3(DM/32, DM/32, NL), 256, 0, stream>>>(Wk, WqkvTh + 512*DM,  WqkvTl + 512*DM,  DM, DM, (size_t)DM*DM, (size_t)1536*DM);
  wt_k<<<dim3(DM/32, DM/32, NL), 256, 0, stream>>>(Wv, WqkvTh + 1024*DM, WqkvTl + 1024*DM, DM, DM, (size_t)DM*DM, (size_t)1536*DM);
  wt_k<<<dim3(DM/32, DM/32, NL), 256, 0, stream>>>(Wo, WoTh, WoTl, DM, DM, (size_t)DM*DM, (size_t)DM*DM);
  wt_k<<<dim3(DFF/32, DM/32, NL), 256, 0, stream>>>(W1, W1Th, W1Tl, DM, DFF, (size_t)DM*DFF, (size_t)DFF*DM);
  wt_k<<<dim3(DM/32, DFF/32, NL), 256, 0, stream>>>(W2, W2Th, W2Tl, DFF, DM, (size_t)DFF*DM, (size_t)DM*DFF);
  wt_k<<<dim3(DM/32, ENCIN/32, 1), 256, 0, stream>>>(W_emb, WeTh, WeTl, ENCIN, DM, 0, 0);
  wt_k<<<dim3(COUT/32, DM/32, 1), 256, 0, stream>>>(W_proj, WpTh, WpTl, DM, COUT, 0, 0);

  // embedding + PE
  hgemm<64,1><<<dim3(DM/64, M/128, 1), 256, 0, stream>>>(
      xeh, xel, WeTh, WeTl, b_emb, nullptr, nullptr,
      x, xh, xl, nullptr, nullptr, nullptr, M, DM, ENCIN, ENCIN);

  for (int il = 0; il < NL; il++) {
    // fused QKV: N = 1536
    hgemm<128,3><<<dim3(1536/128, M/128, 1), 256, 0, stream>>>(
        xh, xl, WqkvTh + (size_t)il*1536*DM, WqkvTl + (size_t)il*1536*DM,
        bq + il*DM, bk + il*DM, bv + il*DM,
        nullptr, qh_, ql_, kh_, kl_, vt_, M, 1536, DM, DM);

    fqk_stat<<<512, 256, 0, stream>>>(qh_, ql_, kh_, kl_,
        cnt_ + (size_t)il*L_*L_, rmx_, rsm_, Mv_);
    sort_k<<<BH, 1024, 0, stream>>>(Mv_, rank_);
    fpv<<<512, 256, 0, stream>>>(qh_, ql_, kh_, kl_, vt_,
        rmx_, rsm_, rank_, ath, atl);

    // Wo: split-K x2 -> partials, reduced in ln2
    hgemm<128,5><<<dim3(DM/128, M/128, 2), 256, 0, stream>>>(
        ath, atl, WoTh + (size_t)il*DM*DM, WoTl + (size_t)il*DM*DM,
        nullptr, nullptr, nullptr,
        partWo, nullptr, nullptr, nullptr, nullptr, nullptr, M, DM, DM, DM/2);
    ln2_k<<<M, 64, 0, stream>>>(x, partWo, 2, bo + il*DM, g1 + il*DM, be1 + il*DM, x, xh, xl);

    // FFN
    hgemm<128,2><<<dim3(DFF/128, M/128, 1), 256, 0, stream>>>(
        xh, xl, W1Th + (size_t)il*DFF*DM, W1Tl + (size_t)il*DFF*DM,
        b1 + il*DFF, nullptr, nullptr,
        nullptr, yh, yl, nullptr, nullptr, nullptr, M, DFF, DM, DM);
    hgemm<128,5><<<dim3(DM/128, M/128, 4), 256, 0, stream>>>(
        yh, yl, W2Th + (size_t)il*DM*DFF, W2Tl + (size_t)il*DM*DFF,
        nullptr, nullptr, nullptr,
        partW2, nullptr, nullptr, nullptr, nullptr, nullptr, M, DM, DFF, DFF/4);
    ln2_k<<<M, 64, 0, stream>>>(x, partW2, 4, b2 + il*DM, g2 + il*DM, be2 + il*DM, x, xh, xl);
  }

  ln2_k<<<M, 64, 0, stream>>>(x, nullptr, 0, nullptr, gN, bN, x, xh, xl);
  hgemm<64,5><<<dim3(COUT/64, M/128, 4), 256, 0, stream>>>(
      xh, xl, WpTh, WpTl, nullptr, nullptr, nullptr,
      partPj, nullptr, nullptr, nullptr, nullptr, nullptr, M, COUT, DM, DM/4);
  rp_k<<<dim3(M*COUT/256), 256, 0, stream>>>(partPj, b_proj, (float*)d_out, M*COUT);
}